// Round 1
// baseline (1117.875 us; speedup 1.0000x reference)
//
#include <hip/hip_runtime.h>

#define NNODE 20000
#define NE    600000
#define DF    128
#define DOUT  16

static inline int ceil_div(int a, int b) { return (a + b - 1) / b; }

__global__ void fill_f32_k(float* a, int n, float v) {
    int i = blockIdx.x * blockDim.x + threadIdx.x;
    if (i < n) a[i] = v;
}

__global__ void deg_col_k(const int* __restrict__ col, const float* __restrict__ w,
                          float* deg, int ne) {
    int e = blockIdx.x * blockDim.x + threadIdx.x;
    if (e < ne) atomicAdd(&deg[col[e]], w[e]);
}

__global__ void deg_dual_k(const int* __restrict__ row, const int* __restrict__ col,
                           const float* __restrict__ w, float* deg_s, float* deg_d, int ne) {
    int e = blockIdx.x * blockDim.x + threadIdx.x;
    if (e < ne) {
        float we = w[e];
        atomicAdd(&deg_s[row[e]], we);
        atomicAdd(&deg_d[col[e]], we);
    }
}

__global__ void to_dinv_k(float* a, int n) {
    int i = blockIdx.x * blockDim.x + threadIdx.x;
    if (i < n) { float d = a[i]; a[i] = d > 0.f ? rsqrtf(d) : 0.f; }
}

__global__ void count_col_k(const int* __restrict__ col, int* cnt, int ne) {
    int e = blockIdx.x * blockDim.x + threadIdx.x;
    if (e < ne) atomicAdd(&cnt[col[e]], 1);
}

// exclusive scan over n (=20000) counts, single block of 1024 threads
__global__ void exscan_k(const int* __restrict__ cnt, int* __restrict__ rowptr, int n) {
    __shared__ int sums[1024];
    int t = threadIdx.x;
    int chunk = (n + 1023) >> 10;
    int b = t * chunk; if (b > n) b = n;
    int e = b + chunk; if (e > n) e = n;
    int s = 0;
    for (int i = b; i < e; ++i) s += cnt[i];
    sums[t] = s;
    __syncthreads();
    for (int off = 1; off < 1024; off <<= 1) {
        int v = (t >= off) ? sums[t - off] : 0;
        __syncthreads();
        sums[t] += v;
        __syncthreads();
    }
    int run = (t == 0) ? 0 : sums[t - 1];
    for (int i = b; i < e; ++i) { rowptr[i] = run; run += cnt[i]; }
    if (t == 1023) rowptr[n] = run;
}

__global__ void scatter_k(const int* __restrict__ row, const int* __restrict__ col,
                          const float* __restrict__ w,
                          const float* __restrict__ dinv_s, const float* __restrict__ dinv_d,
                          const int* __restrict__ rowptr, int* cursor,
                          int* __restrict__ esrc, float* __restrict__ enorm, int ne) {
    int e = blockIdx.x * blockDim.x + threadIdx.x;
    if (e < ne) {
        int r = row[e], c = col[e];
        float nrm = dinv_s[r] * w[e] * dinv_d[c];
        int p = rowptr[c] + atomicAdd(&cursor[c], 1);
        esrc[p] = r;
        enorm[p] = nrm;
    }
}

// pull-SpMM: one wave (64 lanes) per dst node; 2 feature floats per lane (DF=128)
__global__ __launch_bounds__(256) void spmm_k(const float* __restrict__ x,
                                              const int* __restrict__ rowptr,
                                              const int* __restrict__ esrc,
                                              const float* __restrict__ enorm,
                                              const float* __restrict__ dinv_self,
                                              float* __restrict__ out, int n) {
    int wid = (blockIdx.x * blockDim.x + threadIdx.x) >> 6;
    int lane = threadIdx.x & 63;
    if (wid >= n) return;
    float a0 = 0.f, a1 = 0.f;
    if (dinv_self) {
        float dv = dinv_self[wid];
        float sc = dv * dv;
        const float* xs = x + (size_t)wid * DF;
        a0 = xs[lane] * sc;
        a1 = xs[lane + 64] * sc;
    }
    int b = rowptr[wid], e = rowptr[wid + 1];
    int i = b;
    for (; i + 1 < e; i += 2) {
        int s0 = esrc[i], s1 = esrc[i + 1];
        float n0 = enorm[i], n1 = enorm[i + 1];
        const float* x0 = x + (size_t)s0 * DF;
        const float* x1 = x + (size_t)s1 * DF;
        a0 += x0[lane] * n0;
        a1 += x0[lane + 64] * n0;
        a0 += x1[lane] * n1;
        a1 += x1[lane + 64] * n1;
    }
    if (i < e) {
        int s0 = esrc[i];
        float n0 = enorm[i];
        const float* x0 = x + (size_t)s0 * DF;
        a0 += x0[lane] * n0;
        a1 += x0[lane + 64] * n0;
    }
    float* o = out + (size_t)wid * DF;
    o[lane] = a0;
    o[lane + 64] = a1;
}

// out[row, col] = relu(0.5*(A1@Wa + A2@Wb + ba + bb)); A: n x 128, W: 128 x 128
__global__ __launch_bounds__(256) void gemm2_k(const float* __restrict__ A1,
                                               const float* __restrict__ A2,
                                               const float* __restrict__ Wa,
                                               const float* __restrict__ Wb,
                                               const float* __restrict__ ba,
                                               const float* __restrict__ bb,
                                               float* __restrict__ out, int n) {
    __shared__ float As[16][256];
    int r0 = blockIdx.x * 16;
    int t = threadIdx.x;
    for (int idx = t; idx < 16 * 256; idx += 256) {
        int r = idx >> 8, k = idx & 255;
        int row = r0 + r;
        float v = 0.f;
        if (row < n) v = (k < 128) ? A1[(size_t)row * 128 + k] : A2[(size_t)row * 128 + (k - 128)];
        As[r][k] = v;
    }
    __syncthreads();
    int col = t & 127;
    int rb = (t >> 7) * 8;  // 0 or 8
    float acc[8] = {0.f, 0.f, 0.f, 0.f, 0.f, 0.f, 0.f, 0.f};
    for (int k = 0; k < 128; ++k) {
        float wv = Wa[k * 128 + col];
#pragma unroll
        for (int r = 0; r < 8; ++r) acc[r] += As[rb + r][k] * wv;
    }
    for (int k = 0; k < 128; ++k) {
        float wv = Wb[k * 128 + col];
#pragma unroll
        for (int r = 0; r < 8; ++r) acc[r] += As[rb + r][k + 128] * wv;
    }
    float bias = ba[col] + bb[col];
#pragma unroll
    for (int r = 0; r < 8; ++r) {
        int row = r0 + rb + r;
        if (row < n) {
            float v = 0.5f * (acc[r] + bias);
            out[(size_t)row * 128 + col] = v > 0.f ? v : 0.f;
        }
    }
}

// out[row, c] = x[row,:] @ W[:, c] + b[c]; W: 128 x 16
__global__ __launch_bounds__(256) void lin16_k(const float* __restrict__ x,
                                               const float* __restrict__ W,
                                               const float* __restrict__ b,
                                               float* __restrict__ out, int n) {
    int idx = blockIdx.x * blockDim.x + threadIdx.x;
    int row = idx >> 4, c = idx & 15;
    if (row >= n) return;
    const float* xr = x + (size_t)row * 128;
    float acc = b[c];
    for (int k = 0; k < 128; ++k) acc += xr[k] * W[k * 16 + c];
    out[(size_t)row * 16 + c] = acc;
}

extern "C" void kernel_launch(void* const* d_in, const int* in_sizes, int n_in,
                              void* d_out, int out_size, void* d_ws, size_t ws_size,
                              hipStream_t stream) {
    (void)in_sizes; (void)n_in; (void)out_size; (void)ws_size;

    const float* x_gen  = (const float*)d_in[0];
    const float* x_rain = (const float*)d_in[1];
    const int* ei_gg = (const int*)d_in[2];
    const int* ei_gr = (const int*)d_in[3];
    const int* ei_rg = (const int*)d_in[4];
    const int* ei_rr = (const int*)d_in[5];
    const float* w_gg = (const float*)d_in[6];
    const float* w_gr = (const float*)d_in[7];
    const float* w_rg = (const float*)d_in[8];
    const float* w_rr = (const float*)d_in[9];
    const float* W_conv = (const float*)d_in[10];  // [2][4][128][128]
    const float* b_conv = (const float*)d_in[11];  // [2][4][128]
    const float* W_lg = (const float*)d_in[12];
    const float* b_lg = (const float*)d_in[13];
    const float* W_lr = (const float*)d_in[14];
    const float* b_lr = (const float*)d_in[15];

    float* out_gen  = (float*)d_out;
    float* out_rain = out_gen + (size_t)NNODE * DOUT;

    char* p = (char*)d_ws;
    auto alloc = [&](size_t bytes) -> void* {
        void* r = (void*)p;
        p += (bytes + 255) & ~(size_t)255;
        return r;
    };

    // degree / dinv arrays: [gg | gr_s | gr_d | rg_s | rg_d | rr], each 20000 f32
    float* deg = (float*)alloc(6 * NNODE * sizeof(float));
    float* deg_gg   = deg;
    float* deg_gr_s = deg + 1 * NNODE;
    float* deg_gr_d = deg + 2 * NNODE;
    float* deg_rg_s = deg + 3 * NNODE;
    float* deg_rg_d = deg + 4 * NNODE;
    float* deg_rr   = deg + 5 * NNODE;

    int* rowptr[4]; int* cnt[4]; int* esrc[4]; float* enorm[4];
    for (int r = 0; r < 4; ++r) {
        rowptr[r] = (int*)alloc((NNODE + 1) * sizeof(int));
        cnt[r]    = (int*)alloc(NNODE * sizeof(int));
        esrc[r]   = (int*)alloc(NE * sizeof(int));
        enorm[r]  = (float*)alloc(NE * sizeof(float));
    }
    float* agg_gg = (float*)alloc((size_t)NNODE * DF * sizeof(float));
    float* agg_gr = (float*)alloc((size_t)NNODE * DF * sizeof(float));
    float* agg_rg = (float*)alloc((size_t)NNODE * DF * sizeof(float));
    float* agg_rr = (float*)alloc((size_t)NNODE * DF * sizeof(float));
    float* xg_buf = (float*)alloc((size_t)NNODE * DF * sizeof(float));
    float* xr_buf = (float*)alloc((size_t)NNODE * DF * sizeof(float));

    int ge = ceil_div(NE, 256);
    int gn = ceil_div(NNODE, 256);

    // ---- degrees ----
    hipMemsetAsync(deg, 0, 6 * NNODE * sizeof(float), stream);
    fill_f32_k<<<gn, 256, 0, stream>>>(deg_gg, NNODE, 1.0f);  // self-loop weight
    fill_f32_k<<<gn, 256, 0, stream>>>(deg_rr, NNODE, 1.0f);
    deg_col_k <<<ge, 256, 0, stream>>>(ei_gg + NE, w_gg, deg_gg, NE);
    deg_dual_k<<<ge, 256, 0, stream>>>(ei_gr, ei_gr + NE, w_gr, deg_gr_s, deg_gr_d, NE);
    deg_dual_k<<<ge, 256, 0, stream>>>(ei_rg, ei_rg + NE, w_rg, deg_rg_s, deg_rg_d, NE);
    deg_col_k <<<ge, 256, 0, stream>>>(ei_rr + NE, w_rr, deg_rr, NE);
    to_dinv_k <<<ceil_div(6 * NNODE, 256), 256, 0, stream>>>(deg, 6 * NNODE);

    // ---- CSR-by-destination build (per relation) ----
    const int* rows_[4]  = {ei_gg, ei_gr, ei_rg, ei_rr};
    const int* cols_[4]  = {ei_gg + NE, ei_gr + NE, ei_rg + NE, ei_rr + NE};
    const float* ews_[4] = {w_gg, w_gr, w_rg, w_rr};
    const float* dvs_[4] = {deg_gg, deg_gr_s, deg_rg_s, deg_rr};
    const float* dvd_[4] = {deg_gg, deg_gr_d, deg_rg_d, deg_rr};
    for (int r = 0; r < 4; ++r) {
        hipMemsetAsync(cnt[r], 0, NNODE * sizeof(int), stream);
        count_col_k<<<ge, 256, 0, stream>>>(cols_[r], cnt[r], NE);
        exscan_k<<<1, 1024, 0, stream>>>(cnt[r], rowptr[r], NNODE);
        hipMemsetAsync(cnt[r], 0, NNODE * sizeof(int), stream);
        scatter_k<<<ge, 256, 0, stream>>>(rows_[r], cols_[r], ews_[r], dvs_[r], dvd_[r],
                                          rowptr[r], cnt[r], esrc[r], enorm[r], NE);
    }

    // ---- layers ----
    int sb = ceil_div(NNODE, 4);  // 4 waves per block, 1 dst node per wave
    int gb = ceil_div(NNODE, 16);
    for (int l = 0; l < 2; ++l) {
        const float* xg = (l == 0) ? x_gen  : xg_buf;
        const float* xr = (l == 0) ? x_rain : xr_buf;
        spmm_k<<<sb, 256, 0, stream>>>(xg, rowptr[0], esrc[0], enorm[0], deg_gg, agg_gg, NNODE);
        spmm_k<<<sb, 256, 0, stream>>>(xg, rowptr[1], esrc[1], enorm[1], nullptr, agg_gr, NNODE);
        spmm_k<<<sb, 256, 0, stream>>>(xr, rowptr[2], esrc[2], enorm[2], nullptr, agg_rg, NNODE);
        spmm_k<<<sb, 256, 0, stream>>>(xr, rowptr[3], esrc[3], enorm[3], deg_rr, agg_rr, NNODE);
        const float* Wl = W_conv + (size_t)l * 4 * DF * DF;
        const float* bl = b_conv + (size_t)l * 4 * DF;
        gemm2_k<<<gb, 256, 0, stream>>>(agg_gg, agg_rg, Wl + 0 * DF * DF, Wl + 2 * DF * DF,
                                        bl + 0 * DF, bl + 2 * DF, xg_buf, NNODE);
        gemm2_k<<<gb, 256, 0, stream>>>(agg_gr, agg_rr, Wl + 1 * DF * DF, Wl + 3 * DF * DF,
                                        bl + 1 * DF, bl + 3 * DF, xr_buf, NNODE);
    }

    // ---- output heads ----
    lin16_k<<<ceil_div(NNODE * DOUT, 256), 256, 0, stream>>>(xg_buf, W_lg, b_lg, out_gen, NNODE);
    lin16_k<<<ceil_div(NNODE * DOUT, 256), 256, 0, stream>>>(xr_buf, W_lr, b_lr, out_rain, NNODE);
}